// Round 1
// baseline (236.327 us; speedup 1.0000x reference)
//
#include <hip/hip_runtime.h>
#include <hip/hip_bf16.h>

#define LSEQ 50
#define BATCH 4096

typedef __attribute__((ext_vector_type(8))) short bf16x8;
typedef __attribute__((ext_vector_type(4))) float f32x4;

__device__ __forceinline__ unsigned short f2bf(float f) {
    unsigned u = __builtin_bit_cast(unsigned, f);
    u += 0x7fffu + ((u >> 16) & 1u);
    return (unsigned short)(u >> 16);
}
__device__ __forceinline__ float fsigm(float x) {
    return __builtin_amdgcn_rcpf(1.0f + __builtin_amdgcn_exp2f(-1.44269504f * x));
}
__device__ __forceinline__ float ftanh(float x) {
    float e = __builtin_amdgcn_exp2f(2.88539008f * x);
    return 1.0f - 2.0f * __builtin_amdgcn_rcpf(e + 1.0f);
}

// One block = 16 examples, one LSTM direction. 4 waves; wave w owns h-indices
// m in [16w,16w+16) for all 4 gate types (N-tiles {w, w+4, w+8, w+12}), so
// i,f,g,o for a given (example, m) land in the SAME lane (C/D layout:
// col=lane&15 -> m, row=(lane>>4)*4+reg -> example).
__global__ __launch_bounds__(256, 2)
void lstm_kernel(const float* __restrict__ rank_q, const int* __restrict__ qlen,
                 const float* __restrict__ Wih_f, const float* __restrict__ Whh_f,
                 const float* __restrict__ bih_f, const float* __restrict__ bhh_f,
                 const float* __restrict__ Wih_b, const float* __restrict__ Whh_b,
                 const float* __restrict__ bih_b, const float* __restrict__ bhh_b,
                 float* __restrict__ embq)
{
    const int blk = blockIdx.x;
    const int dir = blk >> 8;             // 0 = forward, 1 = backward
    const int b0  = (blk & 255) << 4;     // first example of this block
    const int tid = threadIdx.x;
    const int wv  = tid >> 6;
    const int ln  = tid & 63;
    const int lm  = ln & 15;
    const int lq  = ln >> 4;
    const int m   = (wv << 4) + lm;       // h index owned by this lane

    const float* Wih = dir ? Wih_b : Wih_f;
    const float* Whh = dir ? Whh_b : Whh_f;
    const float* bih = dir ? bih_b : bih_f;
    const float* bhh = dir ? bhh_b : bhh_f;

    // padded rows (+8 bf16) to break the stride-128B/256B bank pattern
    __shared__ __align__(16) unsigned short xbuf[2][16][136];
    __shared__ __align__(16) unsigned short hbuf[2][16][72];

    // B-fragments: [gate j][K-slice s]; n = 64j + m; k = 32s + lq*8 + jj.
    // s=0..3 -> Wih rows (K=128), s=4..5 -> Whh rows (K=64).
    bf16x8 bfrag[4][6];
    float bias[4];
    #pragma unroll
    for (int j = 0; j < 4; ++j) {
        const int n = (j << 6) + m;
        bias[j] = bih[n] + bhh[n];
        #pragma unroll
        for (int s = 0; s < 6; ++s) {
            const int kb = (s << 5) + (lq << 3);
            const float* src = (s < 4) ? (Wih + n * 128 + kb)
                                       : (Whh + n * 64 + (kb - 128));
            float4 w0 = *(const float4*)src;
            float4 w1 = *(const float4*)(src + 4);
            bf16x8 v;
            v[0]=(short)f2bf(w0.x); v[1]=(short)f2bf(w0.y);
            v[2]=(short)f2bf(w0.z); v[3]=(short)f2bf(w0.w);
            v[4]=(short)f2bf(w1.x); v[5]=(short)f2bf(w1.y);
            v[6]=(short)f2bf(w1.z); v[7]=(short)f2bf(w1.w);
            bfrag[j][s] = v;
        }
    }

    int len_e[4];
    #pragma unroll
    for (int r = 0; r < 4; ++r) len_e[r] = qlen[b0 + (lq << 2) + r];

    float cst[4]  = {0.f, 0.f, 0.f, 0.f};
    float qval[4] = {0.f, 0.f, 0.f, 0.f};   // stays 0 for len==0 (zero-pad row)

    // zero hbuf[0] (initial h = 0)
    for (int i = tid; i < 16 * 72; i += 256) ((unsigned short*)hbuf)[i] = 0;

    const int se = tid >> 4;             // staging: example
    const int sd = (tid & 15) << 3;      // staging: d-offset (8 floats/thread)
    {
        const int t0 = dir ? (LSEQ - 1) : 0;
        const float* src = rank_q + ((size_t)(b0 + se) * LSEQ + t0) * 128 + sd;
        float4 a = *(const float4*)src;
        float4 b = *(const float4*)(src + 4);
        bf16x8 v;
        v[0]=(short)f2bf(a.x); v[1]=(short)f2bf(a.y); v[2]=(short)f2bf(a.z); v[3]=(short)f2bf(a.w);
        v[4]=(short)f2bf(b.x); v[5]=(short)f2bf(b.y); v[6]=(short)f2bf(b.z); v[7]=(short)f2bf(b.w);
        *(bf16x8*)&xbuf[0][se][sd] = v;
    }
    __syncthreads();

    for (int it = 0; it < LSEQ; ++it) {
        const int t  = dir ? (LSEQ - 1 - it) : it;
        const int rb = it & 1;
        const int wb = rb ^ 1;

        // A-fragments: row = lane&15 (example), k = 32s + (lane>>4)*8 + jj
        bf16x8 ax0 = *(const bf16x8*)&xbuf[rb][lm][(lq << 3)];
        bf16x8 ax1 = *(const bf16x8*)&xbuf[rb][lm][32 + (lq << 3)];
        bf16x8 ax2 = *(const bf16x8*)&xbuf[rb][lm][64 + (lq << 3)];
        bf16x8 ax3 = *(const bf16x8*)&xbuf[rb][lm][96 + (lq << 3)];
        bf16x8 ah0 = *(const bf16x8*)&hbuf[rb][lm][(lq << 3)];
        bf16x8 ah1 = *(const bf16x8*)&hbuf[rb][lm][32 + (lq << 3)];

        // prefetch next timestep's x (hide HBM latency under MFMA+nonlin)
        float4 nx0, nx1;
        if (it + 1 < LSEQ) {
            const int tn = dir ? (LSEQ - 2 - it) : (it + 1);
            const float* src = rank_q + ((size_t)(b0 + se) * LSEQ + tn) * 128 + sd;
            nx0 = *(const float4*)src;
            nx1 = *(const float4*)(src + 4);
        }

        f32x4 acc[4];
        #pragma unroll
        for (int j = 0; j < 4; ++j) {
            f32x4 a = {bias[j], bias[j], bias[j], bias[j]};  // bias via acc-init
            a = __builtin_amdgcn_mfma_f32_16x16x32_bf16(ax0, bfrag[j][0], a, 0, 0, 0);
            a = __builtin_amdgcn_mfma_f32_16x16x32_bf16(ax1, bfrag[j][1], a, 0, 0, 0);
            a = __builtin_amdgcn_mfma_f32_16x16x32_bf16(ax2, bfrag[j][2], a, 0, 0, 0);
            a = __builtin_amdgcn_mfma_f32_16x16x32_bf16(ax3, bfrag[j][3], a, 0, 0, 0);
            a = __builtin_amdgcn_mfma_f32_16x16x32_bf16(ah0, bfrag[j][4], a, 0, 0, 0);
            a = __builtin_amdgcn_mfma_f32_16x16x32_bf16(ah1, bfrag[j][5], a, 0, 0, 0);
            acc[j] = a;
        }

        #pragma unroll
        for (int r = 0; r < 4; ++r) {
            float ig = fsigm(acc[0][r]);
            float fg = fsigm(acc[1][r]);
            float gg = ftanh(acc[2][r]);
            float og = fsigm(acc[3][r]);
            float cn = fg * cst[r] + ig * gg;
            cst[r] = cn;
            float hn = og * ftanh(cn);
            if (t == len_e[r] - 1) qval[r] = hn;           // captured in fp32
            hbuf[wb][(lq << 2) + r][m] = f2bf(hn);
        }

        if (it + 1 < LSEQ) {
            bf16x8 v;
            v[0]=(short)f2bf(nx0.x); v[1]=(short)f2bf(nx0.y); v[2]=(short)f2bf(nx0.z); v[3]=(short)f2bf(nx0.w);
            v[4]=(short)f2bf(nx1.x); v[5]=(short)f2bf(nx1.y); v[6]=(short)f2bf(nx1.z); v[7]=(short)f2bf(nx1.w);
            *(bf16x8*)&xbuf[wb][se][sd] = v;
        }
        __syncthreads();   // double-buffered x and h -> single barrier/step
    }

    #pragma unroll
    for (int r = 0; r < 4; ++r)
        embq[(size_t)(b0 + (lq << 2) + r) * 128 + (dir << 6) + m] = qval[r];
}

// One wave = one example, lane = channel c. Only the 3 windows containing
// mat-row-2 survive low-high cancellation: fc1_w[2] (conv1 w=2), fc1_w[4]
// (conv2 w=1), fc1_w[5] (conv3). All fp32.
__global__ __launch_bounds__(256)
void score_kernel(const int* __restrict__ r_idx, const int* __restrict__ a_idx,
                  const int* __restrict__ acc_idx,
                  const float* __restrict__ ru, const float* __restrict__ au,
                  const float* __restrict__ embq,
                  const float* __restrict__ c1w, const float* __restrict__ c1b,
                  const float* __restrict__ c2w, const float* __restrict__ c2b,
                  const float* __restrict__ c3w, const float* __restrict__ c3b,
                  const float* __restrict__ fc1w, const float* __restrict__ fc2w,
                  float* __restrict__ diff)
{
    const int tid = threadIdx.x;
    const int wv  = tid >> 6;
    const int c   = tid & 63;
    const int b   = (blockIdx.x << 2) + wv;

    __shared__ __align__(16) float emb[4][4][128];   // [example][r,q,a,acc][d]
    {
        const int e  = tid >> 6;
        const int v  = (tid >> 4) & 3;
        const int d0 = (tid & 15) << 3;
        const int bb = (blockIdx.x << 2) + e;
        const float* src;
        if      (v == 0) src = ru   + (size_t)r_idx[bb]   * 128 + d0;
        else if (v == 1) src = embq + (size_t)bb          * 128 + d0;
        else if (v == 2) src = au   + (size_t)a_idx[bb]   * 128 + d0;
        else             src = au   + (size_t)acc_idx[bb] * 128 + d0;
        float4 x0 = *(const float4*)src;
        float4 x1 = *(const float4*)(src + 4);
        *(float4*)&emb[e][v][d0]     = x0;
        *(float4*)&emb[e][v][d0 + 4] = x1;
    }
    __syncthreads();

    float d1a=0.f, d1x=0.f, d2q=0.f, d2a=0.f, d2x=0.f;
    float d3r=0.f, d3q=0.f, d3a=0.f, d3x=0.f;
    const float* w1p  = c1w + c * 128;
    const float* w20p = c2w + c * 256;
    const float* w30p = c3w + c * 384;
    #pragma unroll 2
    for (int d = 0; d < 128; d += 4) {
        float4 er  = *(const float4*)&emb[wv][0][d];
        float4 eq  = *(const float4*)&emb[wv][1][d];
        float4 ea  = *(const float4*)&emb[wv][2][d];
        float4 ex  = *(const float4*)&emb[wv][3][d];
        float4 w1  = *(const float4*)(w1p + d);
        float4 w20 = *(const float4*)(w20p + d);
        float4 w21 = *(const float4*)(w20p + 128 + d);
        float4 w30 = *(const float4*)(w30p + d);
        float4 w31 = *(const float4*)(w30p + 128 + d);
        float4 w32 = *(const float4*)(w30p + 256 + d);
        d1a += w1.x*ea.x + w1.y*ea.y + w1.z*ea.z + w1.w*ea.w;
        d1x += w1.x*ex.x + w1.y*ex.y + w1.z*ex.z + w1.w*ex.w;
        d2q += w20.x*eq.x + w20.y*eq.y + w20.z*eq.z + w20.w*eq.w;
        d2a += w21.x*ea.x + w21.y*ea.y + w21.z*ea.z + w21.w*ea.w;
        d2x += w21.x*ex.x + w21.y*ex.y + w21.z*ex.z + w21.w*ex.w;
        d3r += w30.x*er.x + w30.y*er.y + w30.z*er.z + w30.w*er.w;
        d3q += w31.x*eq.x + w31.y*eq.y + w31.z*eq.z + w31.w*eq.w;
        d3a += w32.x*ea.x + w32.y*ea.y + w32.z*ea.z + w32.w*ea.w;
        d3x += w32.x*ex.x + w32.y*ex.y + w32.z*ex.z + w32.w*ex.w;
    }
    const float b1 = c1b[c], b2 = c2b[c], b3 = c3b[c];
    const float r1 = fmaxf(d1a + b1, 0.f)             - fmaxf(d1x + b1, 0.f);
    const float r2 = fmaxf(d2q + d2a + b2, 0.f)       - fmaxf(d2q + d2x + b2, 0.f);
    const float r3 = fmaxf(d3r + d3q + d3a + b3, 0.f) - fmaxf(d3r + d3q + d3x + b3, 0.f);
    float term = fc2w[c] * (fc1w[2] * r1 + fc1w[4] * r2 + fc1w[5] * r3);
    #pragma unroll
    for (int off = 32; off; off >>= 1) term += __shfl_down(term, off);
    if (c == 0) diff[b] = term;
}

__global__ void reduce_kernel(const float* __restrict__ diff, float* __restrict__ out)
{
    __shared__ float s[256];
    const int tid = threadIdx.x;
    float v = 0.f;
    for (int i = tid; i < BATCH; i += 256) v += diff[i];   // fixed order: deterministic
    s[tid] = v;
    __syncthreads();
    for (int st = 128; st > 0; st >>= 1) {
        if (tid < st) s[tid] += s[tid + st];
        __syncthreads();
    }
    if (tid == 0) out[0] = s[0];
}

extern "C" void kernel_launch(void* const* d_in, const int* in_sizes, int n_in,
                              void* d_out, int out_size, void* d_ws, size_t ws_size,
                              hipStream_t stream) {
    (void)in_sizes; (void)n_in; (void)out_size; (void)ws_size;
    const int*   r_idx   = (const int*)d_in[0];
    const int*   a_idx   = (const int*)d_in[1];
    const int*   acc_idx = (const int*)d_in[2];
    const float* rank_q  = (const float*)d_in[3];
    const int*   qlen    = (const int*)d_in[4];
    const float* ru      = (const float*)d_in[5];
    const float* au      = (const float*)d_in[6];
    const float* Wih_f   = (const float*)d_in[7];
    const float* Whh_f   = (const float*)d_in[8];
    const float* bih_f   = (const float*)d_in[9];
    const float* bhh_f   = (const float*)d_in[10];
    const float* Wih_b   = (const float*)d_in[11];
    const float* Whh_b   = (const float*)d_in[12];
    const float* bih_b   = (const float*)d_in[13];
    const float* bhh_b   = (const float*)d_in[14];
    const float* c1w     = (const float*)d_in[15];
    const float* c1b     = (const float*)d_in[16];
    const float* c2w     = (const float*)d_in[17];
    const float* c2b     = (const float*)d_in[18];
    const float* c3w     = (const float*)d_in[19];
    const float* c3b     = (const float*)d_in[20];
    const float* fc1w    = (const float*)d_in[21];
    const float* fc2w    = (const float*)d_in[23];

    float* embq = (float*)d_ws;                       // [4096][128] fp32
    float* diff = embq + (size_t)BATCH * 128;         // [4096] fp32

    lstm_kernel<<<512, 256, 0, stream>>>(rank_q, qlen, Wih_f, Whh_f, bih_f, bhh_f,
                                         Wih_b, Whh_b, bih_b, bhh_b, embq);
    score_kernel<<<BATCH / 4, 256, 0, stream>>>(r_idx, a_idx, acc_idx, ru, au, embq,
                                                c1w, c1b, c2w, c2b, c3w, c3b,
                                                fc1w, fc2w, diff);
    reduce_kernel<<<1, 256, 0, stream>>>(diff, (float*)d_out);
}

// Round 2
// 108.390 us; speedup vs baseline: 2.1803x; 2.1803x over previous
//
#include <hip/hip_runtime.h>
#include <hip/hip_bf16.h>

#define LSEQ 50
#define BATCH 4096

typedef __attribute__((ext_vector_type(8))) short bf16x8;
typedef __attribute__((ext_vector_type(4))) float f32x4;

__device__ __forceinline__ unsigned short f2bf(float f) {
    unsigned u = __builtin_bit_cast(unsigned, f);
    u += 0x7fffu + ((u >> 16) & 1u);
    return (unsigned short)(u >> 16);
}
__device__ __forceinline__ float fsigm(float x) {
    return __builtin_amdgcn_rcpf(1.0f + __builtin_amdgcn_exp2f(-1.44269504f * x));
}
__device__ __forceinline__ float ftanh(float x) {
    float e = __builtin_amdgcn_exp2f(2.88539008f * x);
    return 1.0f - 2.0f * __builtin_amdgcn_rcpf(e + 1.0f);
}

// ---------------- LSTM (unchanged from R0 — passing, ~55us, next target) ----
__global__ __launch_bounds__(256, 2)
void lstm_kernel(const float* __restrict__ rank_q, const int* __restrict__ qlen,
                 const float* __restrict__ Wih_f, const float* __restrict__ Whh_f,
                 const float* __restrict__ bih_f, const float* __restrict__ bhh_f,
                 const float* __restrict__ Wih_b, const float* __restrict__ Whh_b,
                 const float* __restrict__ bih_b, const float* __restrict__ bhh_b,
                 float* __restrict__ embq)
{
    const int blk = blockIdx.x;
    const int dir = blk >> 8;
    const int b0  = (blk & 255) << 4;
    const int tid = threadIdx.x;
    const int wv  = tid >> 6;
    const int ln  = tid & 63;
    const int lm  = ln & 15;
    const int lq  = ln >> 4;
    const int m   = (wv << 4) + lm;

    const float* Wih = dir ? Wih_b : Wih_f;
    const float* Whh = dir ? Whh_b : Whh_f;
    const float* bih = dir ? bih_b : bih_f;
    const float* bhh = dir ? bhh_b : bhh_f;

    __shared__ __align__(16) unsigned short xbuf[2][16][136];
    __shared__ __align__(16) unsigned short hbuf[2][16][72];

    bf16x8 bfrag[4][6];
    float bias[4];
    #pragma unroll
    for (int j = 0; j < 4; ++j) {
        const int n = (j << 6) + m;
        bias[j] = bih[n] + bhh[n];
        #pragma unroll
        for (int s = 0; s < 6; ++s) {
            const int kb = (s << 5) + (lq << 3);
            const float* src = (s < 4) ? (Wih + n * 128 + kb)
                                       : (Whh + n * 64 + (kb - 128));
            float4 w0 = *(const float4*)src;
            float4 w1 = *(const float4*)(src + 4);
            bf16x8 v;
            v[0]=(short)f2bf(w0.x); v[1]=(short)f2bf(w0.y);
            v[2]=(short)f2bf(w0.z); v[3]=(short)f2bf(w0.w);
            v[4]=(short)f2bf(w1.x); v[5]=(short)f2bf(w1.y);
            v[6]=(short)f2bf(w1.z); v[7]=(short)f2bf(w1.w);
            bfrag[j][s] = v;
        }
    }

    int len_e[4];
    #pragma unroll
    for (int r = 0; r < 4; ++r) len_e[r] = qlen[b0 + (lq << 2) + r];

    float cst[4]  = {0.f, 0.f, 0.f, 0.f};
    float qval[4] = {0.f, 0.f, 0.f, 0.f};

    for (int i = tid; i < 16 * 72; i += 256) ((unsigned short*)hbuf)[i] = 0;

    const int se = tid >> 4;
    const int sd = (tid & 15) << 3;
    {
        const int t0 = dir ? (LSEQ - 1) : 0;
        const float* src = rank_q + ((size_t)(b0 + se) * LSEQ + t0) * 128 + sd;
        float4 a = *(const float4*)src;
        float4 b = *(const float4*)(src + 4);
        bf16x8 v;
        v[0]=(short)f2bf(a.x); v[1]=(short)f2bf(a.y); v[2]=(short)f2bf(a.z); v[3]=(short)f2bf(a.w);
        v[4]=(short)f2bf(b.x); v[5]=(short)f2bf(b.y); v[6]=(short)f2bf(b.z); v[7]=(short)f2bf(b.w);
        *(bf16x8*)&xbuf[0][se][sd] = v;
    }
    __syncthreads();

    for (int it = 0; it < LSEQ; ++it) {
        const int t  = dir ? (LSEQ - 1 - it) : it;
        const int rb = it & 1;
        const int wb = rb ^ 1;

        bf16x8 ax0 = *(const bf16x8*)&xbuf[rb][lm][(lq << 3)];
        bf16x8 ax1 = *(const bf16x8*)&xbuf[rb][lm][32 + (lq << 3)];
        bf16x8 ax2 = *(const bf16x8*)&xbuf[rb][lm][64 + (lq << 3)];
        bf16x8 ax3 = *(const bf16x8*)&xbuf[rb][lm][96 + (lq << 3)];
        bf16x8 ah0 = *(const bf16x8*)&hbuf[rb][lm][(lq << 3)];
        bf16x8 ah1 = *(const bf16x8*)&hbuf[rb][lm][32 + (lq << 3)];

        float4 nx0, nx1;
        if (it + 1 < LSEQ) {
            const int tn = dir ? (LSEQ - 2 - it) : (it + 1);
            const float* src = rank_q + ((size_t)(b0 + se) * LSEQ + tn) * 128 + sd;
            nx0 = *(const float4*)src;
            nx1 = *(const float4*)(src + 4);
        }

        f32x4 acc[4];
        #pragma unroll
        for (int j = 0; j < 4; ++j) {
            f32x4 a = {bias[j], bias[j], bias[j], bias[j]};
            a = __builtin_amdgcn_mfma_f32_16x16x32_bf16(ax0, bfrag[j][0], a, 0, 0, 0);
            a = __builtin_amdgcn_mfma_f32_16x16x32_bf16(ax1, bfrag[j][1], a, 0, 0, 0);
            a = __builtin_amdgcn_mfma_f32_16x16x32_bf16(ax2, bfrag[j][2], a, 0, 0, 0);
            a = __builtin_amdgcn_mfma_f32_16x16x32_bf16(ax3, bfrag[j][3], a, 0, 0, 0);
            a = __builtin_amdgcn_mfma_f32_16x16x32_bf16(ah0, bfrag[j][4], a, 0, 0, 0);
            a = __builtin_amdgcn_mfma_f32_16x16x32_bf16(ah1, bfrag[j][5], a, 0, 0, 0);
            acc[j] = a;
        }

        #pragma unroll
        for (int r = 0; r < 4; ++r) {
            float ig = fsigm(acc[0][r]);
            float fg = fsigm(acc[1][r]);
            float gg = ftanh(acc[2][r]);
            float og = fsigm(acc[3][r]);
            float cn = fg * cst[r] + ig * gg;
            cst[r] = cn;
            float hn = og * ftanh(cn);
            if (t == len_e[r] - 1) qval[r] = hn;
            hbuf[wb][(lq << 2) + r][m] = f2bf(hn);
        }

        if (it + 1 < LSEQ) {
            bf16x8 v;
            v[0]=(short)f2bf(nx0.x); v[1]=(short)f2bf(nx0.y); v[2]=(short)f2bf(nx0.z); v[3]=(short)f2bf(nx0.w);
            v[4]=(short)f2bf(nx1.x); v[5]=(short)f2bf(nx1.y); v[6]=(short)f2bf(nx1.z); v[7]=(short)f2bf(nx1.w);
            *(bf16x8*)&xbuf[wb][se][sd] = v;
        }
        __syncthreads();
    }

    #pragma unroll
    for (int r = 0; r < 4; ++r)
        embq[(size_t)(b0 + (lq << 2) + r) * 128 + (dir << 6) + m] = qval[r];
}

// ---- prep: transpose conv weights to [m][j][c][4] so lane=c reads are
// contiguous 1KB/wave. m: 0=c1w, 1=c2w row0, 2=c2w row1, 3..5=c3w rows 0..2.
__global__ __launch_bounds__(256)
void prep_kernel(const float* __restrict__ c1w, const float* __restrict__ c2w,
                 const float* __restrict__ c3w, float* __restrict__ T)
{
    const int id = blockIdx.x * 256 + threadIdx.x;   // 6*32*64*4 = 49152
    const int m  = id >> 13;
    const int rem = id & 8191;
    const int j  = rem >> 8;
    const int q  = rem & 255;
    const int c  = q >> 2;
    const int d  = (j << 2) + (q & 3);
    const float* src;
    switch (m) {
        case 0:  src = c1w + c * 128 + d;       break;
        case 1:  src = c2w + c * 256 + d;       break;
        case 2:  src = c2w + c * 256 + 128 + d; break;
        case 3:  src = c3w + c * 384 + d;       break;
        case 4:  src = c3w + c * 384 + 128 + d; break;
        default: src = c3w + c * 384 + 256 + d; break;
    }
    T[id] = *src;
}

// Block = 16 examples, wave = 4 examples, lane = channel. Weights from the
// transposed table (coalesced, register-cached across 4 examples);
// embeddings from LDS as wave-uniform broadcasts. All fp32.
__global__ __launch_bounds__(256)
void score_kernel(const int* __restrict__ r_idx, const int* __restrict__ a_idx,
                  const int* __restrict__ acc_idx,
                  const float* __restrict__ ru, const float* __restrict__ au,
                  const float* __restrict__ embq, const float* __restrict__ T,
                  const float* __restrict__ c1b, const float* __restrict__ c2b,
                  const float* __restrict__ c3b,
                  const float* __restrict__ fc1w, const float* __restrict__ fc2w,
                  float* __restrict__ diff)
{
    const int tid = threadIdx.x;
    const int wv  = tid >> 6;
    const int c   = tid & 63;
    const int b0  = blockIdx.x << 4;

    __shared__ __align__(16) float emb[64][132];   // row = local_e*4 + v; +4 pad de-banks staging
    {
        const int row = tid & 63;                  // e*4 + v
        const int e   = row >> 2, v = row & 3;
        const int seg = (tid >> 6) << 5;           // 32-float segment
        const int bb  = b0 + e;
        const float* src = (v == 0) ? ru   + (size_t)r_idx[bb]   * 128 :
                           (v == 1) ? embq + (size_t)bb          * 128 :
                           (v == 2) ? au   + (size_t)a_idx[bb]   * 128 :
                                      au   + (size_t)acc_idx[bb] * 128;
        #pragma unroll
        for (int i = 0; i < 8; ++i) {
            float4 x = *(const float4*)(src + seg + (i << 2));
            *(float4*)&emb[row][seg + (i << 2)] = x;
        }
    }
    __syncthreads();

    float acc[4][9];
    #pragma unroll
    for (int e = 0; e < 4; ++e)
        #pragma unroll
        for (int k = 0; k < 9; ++k) acc[e][k] = 0.f;

    const float4* Tq = (const float4*)T;           // m-stride = 2048 float4
    for (int j = 0; j < 32; ++j) {
        const float4* wq = Tq + j * 64 + c;
        const float4 w1  = wq[0];
        const float4 w20 = wq[2048];
        const float4 w21 = wq[4096];
        const float4 w30 = wq[6144];
        const float4 w31 = wq[8192];
        const float4 w32 = wq[10240];
        const int jd = j << 2;
        #pragma unroll
        for (int e = 0; e < 4; ++e) {
            const int br = ((wv << 2) + e) << 2;
            const float4 er = *(const float4*)&emb[br + 0][jd];
            const float4 eq = *(const float4*)&emb[br + 1][jd];
            const float4 ea = *(const float4*)&emb[br + 2][jd];
            const float4 ex = *(const float4*)&emb[br + 3][jd];
            acc[e][0] += w1.x*ea.x  + w1.y*ea.y  + w1.z*ea.z  + w1.w*ea.w;
            acc[e][1] += w1.x*ex.x  + w1.y*ex.y  + w1.z*ex.z  + w1.w*ex.w;
            acc[e][2] += w20.x*eq.x + w20.y*eq.y + w20.z*eq.z + w20.w*eq.w;
            acc[e][3] += w21.x*ea.x + w21.y*ea.y + w21.z*ea.z + w21.w*ea.w;
            acc[e][4] += w21.x*ex.x + w21.y*ex.y + w21.z*ex.z + w21.w*ex.w;
            acc[e][5] += w30.x*er.x + w30.y*er.y + w30.z*er.z + w30.w*er.w;
            acc[e][6] += w31.x*eq.x + w31.y*eq.y + w31.z*eq.z + w31.w*eq.w;
            acc[e][7] += w32.x*ea.x + w32.y*ea.y + w32.z*ea.z + w32.w*ea.w;
            acc[e][8] += w32.x*ex.x + w32.y*ex.y + w32.z*ex.z + w32.w*ex.w;
        }
    }

    const float b1 = c1b[c], b2 = c2b[c], b3 = c3b[c], f2 = fc2w[c];
    const float f12 = fc1w[2], f14 = fc1w[4], f15 = fc1w[5];
    #pragma unroll
    for (int e = 0; e < 4; ++e) {
        const float r1 = fmaxf(acc[e][0] + b1, 0.f) - fmaxf(acc[e][1] + b1, 0.f);
        const float r2 = fmaxf(acc[e][2] + acc[e][3] + b2, 0.f)
                       - fmaxf(acc[e][2] + acc[e][4] + b2, 0.f);
        const float r3 = fmaxf(acc[e][5] + acc[e][6] + acc[e][7] + b3, 0.f)
                       - fmaxf(acc[e][5] + acc[e][6] + acc[e][8] + b3, 0.f);
        float term = f2 * (f12 * r1 + f14 * r2 + f15 * r3);
        #pragma unroll
        for (int off = 32; off; off >>= 1) term += __shfl_down(term, off);
        if (c == 0) diff[b0 + (wv << 2) + e] = term;
    }
}

__global__ void reduce_kernel(const float* __restrict__ diff, float* __restrict__ out)
{
    __shared__ float s[256];
    const int tid = threadIdx.x;
    float v = 0.f;
    for (int i = tid; i < BATCH; i += 256) v += diff[i];
    s[tid] = v;
    __syncthreads();
    for (int st = 128; st > 0; st >>= 1) {
        if (tid < st) s[tid] += s[tid + st];
        __syncthreads();
    }
    if (tid == 0) out[0] = s[0];
}

extern "C" void kernel_launch(void* const* d_in, const int* in_sizes, int n_in,
                              void* d_out, int out_size, void* d_ws, size_t ws_size,
                              hipStream_t stream) {
    (void)in_sizes; (void)n_in; (void)out_size; (void)ws_size;
    const int*   r_idx   = (const int*)d_in[0];
    const int*   a_idx   = (const int*)d_in[1];
    const int*   acc_idx = (const int*)d_in[2];
    const float* rank_q  = (const float*)d_in[3];
    const int*   qlen    = (const int*)d_in[4];
    const float* ru      = (const float*)d_in[5];
    const float* au      = (const float*)d_in[6];
    const float* Wih_f   = (const float*)d_in[7];
    const float* Whh_f   = (const float*)d_in[8];
    const float* bih_f   = (const float*)d_in[9];
    const float* bhh_f   = (const float*)d_in[10];
    const float* Wih_b   = (const float*)d_in[11];
    const float* Whh_b   = (const float*)d_in[12];
    const float* bih_b   = (const float*)d_in[13];
    const float* bhh_b   = (const float*)d_in[14];
    const float* c1w     = (const float*)d_in[15];
    const float* c1b     = (const float*)d_in[16];
    const float* c2w     = (const float*)d_in[17];
    const float* c2b     = (const float*)d_in[18];
    const float* c3w     = (const float*)d_in[19];
    const float* c3b     = (const float*)d_in[20];
    const float* fc1w    = (const float*)d_in[21];
    const float* fc2w    = (const float*)d_in[23];

    float* embq = (float*)d_ws;                       // [4096][128] fp32
    float* diff = embq + (size_t)BATCH * 128;         // [4096]
    float* T    = diff + BATCH;                       // [49152] transposed weights

    prep_kernel<<<192, 256, 0, stream>>>(c1w, c2w, c3w, T);
    lstm_kernel<<<512, 256, 0, stream>>>(rank_q, qlen, Wih_f, Whh_f, bih_f, bhh_f,
                                         Wih_b, Whh_b, bih_b, bhh_b, embq);
    score_kernel<<<BATCH / 16, 256, 0, stream>>>(r_idx, a_idx, acc_idx, ru, au, embq, T,
                                                 c1b, c2b, c3b, fc1w, fc2w, diff);
    reduce_kernel<<<1, 256, 0, stream>>>(diff, (float*)d_out);
}